// Round 1
// baseline (57.341 us; speedup 1.0000x reference)
//
#include <hip/hip_runtime.h>

// ---------------------------------------------------------------------------
// LIIF forward, MI355X.  Structure:
//   k_prepw     : transpose weights to K-contiguous f16 layouts in ws
//   k_transpose : x [B,C,H,W] f32 -> xt [B,H,W,C] f16
//   k_stage1    : P[b,pix,128] = unfold3x3(x) @ w0[0:576] + b0   (conv-GEMM, f16 MFMA)
//   k_stage2    : per query-corner: h0 = relu(P[lin] + rel terms) -> 3x(128x128) -> 128x64
//                 -> area-weighted corner combine -> out f32
// B=2, C=64, H=W=128, Q=8192. Rows per stage2 block: 32 queries x 4 corners = 128.
// ---------------------------------------------------------------------------

typedef unsigned short U16;
using f16x8 = __attribute__((ext_vector_type(8))) _Float16;
using f32x4 = __attribute__((ext_vector_type(4))) float;
using u16x8 = __attribute__((ext_vector_type(8))) U16;
using u16x4 = __attribute__((ext_vector_type(4))) U16;

// ws layout (f16 element offsets)
#define XT_OFF   0          // 2*128*128*64 = 2,097,152
#define P_OFF    2097152    // 2*16384*128  = 4,194,304
#define W0T_OFF  6291456    // 128*576      = 73,728   w0t[o][kpos*64+c]
#define W1T_OFF  6365184    // 3 * 128*128  = 49,152   wLt[o][k]
#define W4T_OFF  6414336    // 64*128       = 8,192    w4t[o][k]
// total 6,422,528 elems = 12.85 MB of ws

__device__ __forceinline__ float h2f(U16 u){ _Float16 h; __builtin_memcpy(&h,&u,2); return (float)h; }
__device__ __forceinline__ U16 f2h(float f){ _Float16 h = (_Float16)f; U16 u; __builtin_memcpy(&u,&h,2); return u; }

__device__ __forceinline__ int nearest_idx(float g){
  float t = (g + 1.0f) * 128.0f;   // exact (x2^7)
  t = (t - 1.0f) * 0.5f;           // exact
  float r = rintf(t);              // half-even == np.round
  r = fminf(fmaxf(r, 0.0f), 127.0f);
  return (int)r;
}
__device__ __forceinline__ float seqv(int i){ return -0.9921875f + 0.015625f*(float)i; }

// corner: 0:(-1,-1) 1:(-1,+1) 2:(+1,-1) 3:(+1,+1)  (vx outer, vy inner as in ref)
__device__ __forceinline__ void corner_calc(float c0, float c1, int corner,
                                            int& iy, int& ix, float& rel0, float& rel1){
  const float rx = 0.0078125f;
  float sx = (corner & 2) ? rx : -rx;
  float sy = (corner & 1) ? rx : -rx;
  float a0 = c0 + sx; a0 = a0 + 1e-6f; a0 = fminf(fmaxf(a0, -1.0f + 1e-6f), 1.0f - 1e-6f);
  float a1 = c1 + sy; a1 = a1 + 1e-6f; a1 = fminf(fmaxf(a1, -1.0f + 1e-6f), 1.0f - 1e-6f);
  iy = nearest_idx(a0);
  ix = nearest_idx(a1);
  rel0 = (c0 - seqv(ix)) * 128.0f;   // NOTE ref quirk: rel0 uses seq[ix]
  rel1 = (c1 - seqv(iy)) * 128.0f;
}

// ---------------------------------------------------------------------------
__global__ __launch_bounds__(256) void k_prepw(const float* __restrict__ w0,
    const float* __restrict__ w1, const float* __restrict__ w2,
    const float* __restrict__ w3, const float* __restrict__ w4,
    U16* __restrict__ ws)
{
  int i = blockIdx.x * 256 + threadIdx.x;   // grid 512 -> 131072 == total elems
  float v; int dst;
  if (i < 73728) {                 // w0t[o][kpos*64+c] = w0[(c*9+kpos)*128+o]
    int o = i / 576, k = i % 576;
    int kpos = k >> 6, c = k & 63;
    v = w0[(c*9 + kpos)*128 + o];
    dst = W0T_OFF + i;
  } else if (i < 122880) {         // wLt[o][k] = wL[k*128+o]
    int j = i - 73728; int L = j >> 14; int loc = j & 16383;
    int o = loc >> 7, k = loc & 127;
    const float* src = (L == 0) ? w1 : (L == 1) ? w2 : w3;
    v = src[(k << 7) + o];
    dst = W1T_OFF + j;
  } else {                         // w4t[o][k] = w4[k*64+o]
    int j = i - 122880; int o = j >> 7, k = j & 127;
    v = w4[(k << 6) + o];
    dst = W4T_OFF + j;
  }
  ws[dst] = f2h(v);
}

// ---------------------------------------------------------------------------
// x [B,C,H,W] f32 -> xt [B,H,W,C] f16.  Block: (b, y, half-of-x). 64x64 LDS tile.
__global__ __launch_bounds__(256) void k_transpose(const float* __restrict__ x,
                                                   U16* __restrict__ xt)
{
  __shared__ U16 t[64 * 72];   // [c][col^swz], stride 72 (16B-aligned rows)
  const int tid = threadIdx.x, bid = blockIdx.x;
  const int xh = bid & 1, y = (bid >> 1) & 127, b = bid >> 8;
  const int x0 = xh << 6;
  {
    int cc = tid & 63, seg = tid >> 6;
    const float* src = x + (((size_t)((b << 6) + cc)) << 14) + (y << 7) + x0 + (seg << 4);
    U16 h[16];
    #pragma unroll
    for (int e = 0; e < 16; e += 4) {
      float4 v = *(const float4*)(src + e);
      h[e] = f2h(v.x); h[e+1] = f2h(v.y); h[e+2] = f2h(v.z); h[e+3] = f2h(v.w);
    }
    int sw = (cc & 7) << 3;
    u16x8 lo, hi;
    #pragma unroll
    for (int e = 0; e < 8; ++e) { lo[e] = h[e]; hi[e] = h[e+8]; }
    *(u16x8*)(&t[cc*72 + (((seg << 4)    ) ^ sw)]) = lo;
    *(u16x8*)(&t[cc*72 + (((seg << 4) + 8) ^ sw)]) = hi;
  }
  __syncthreads();
  {
    int xx = tid & 63, seg = tid >> 6;
    U16 h[16];
    #pragma unroll
    for (int j = 0; j < 16; ++j) {
      int c = (seg << 4) + j;
      h[j] = t[c*72 + (xx ^ ((c & 7) << 3))];
    }
    U16* dst = xt + ((size_t)(((b << 7) + y) << 7) + x0 + xx) * 64 + (seg << 4);
    u16x8 lo, hi;
    #pragma unroll
    for (int e = 0; e < 8; ++e) { lo[e] = h[e]; hi[e] = h[e+8]; }
    *(u16x8*)(dst) = lo;
    *(u16x8*)(dst + 8) = hi;
  }
}

// ---------------------------------------------------------------------------
// Stage 1: conv3x3-as-GEMM.  Block = (b, y): M=128 outch x N=128 pixels, K=9*64.
// A (weights, w0t) from global (L1/L2-hot); B (x rows) in XOR-swizzled LDS.
__global__ __launch_bounds__(256) void k_stage1(const U16* __restrict__ xt,
                                                const U16* __restrict__ w0t,
                                                const float* __restrict__ b0,
                                                U16* __restrict__ P)
{
  __shared__ U16 araw[3 * 130 * 64];   // [dy][xp][c^((xp&7)<<3)], xp=x+dx+1 in [0,129]
  const int tid = threadIdx.x;
  const int bid = blockIdx.x;
  const int b = bid >> 7, y = bid & 127;

  const u16x8 zero8 = {0,0,0,0,0,0,0,0};
  for (int dy = 0; dy < 3; ++dy) {
    int yy = y + dy - 1;
    #pragma unroll
    for (int it = 0; it < 4; ++it) {
      int u = tid + it * 256;          // 1024 units of 8 f16
      int xp = 1 + (u >> 3);
      int c0 = (u & 7) << 3;
      u16x8 v = zero8;
      if (yy >= 0 && yy < 128) {
        int csrc = c0 ^ ((xp & 7) << 3);
        v = *(const u16x8*)(xt + ((size_t)(((b << 7) + yy) << 7) + (xp - 1)) * 64 + csrc);
      }
      *(u16x8*)(&araw[(dy * 130 + xp) * 64 + c0]) = v;
    }
  }
  if (tid < 48) {                      // zero pad columns xp=0 and xp=129
    int dy = tid >> 4, which = (tid >> 3) & 1, c0 = (tid & 7) << 3;
    int xp = which ? 129 : 0;
    *(u16x8*)(&araw[(dy * 130 + xp) * 64 + c0]) = zero8;
  }
  __syncthreads();

  const int wv = tid >> 6, ln = tid & 63;
  const int lrow = ln & 15, lg = ln >> 4;

  f32x4 acc[2][8];
  #pragma unroll
  for (int m = 0; m < 2; ++m)
    #pragma unroll
    for (int n = 0; n < 8; ++n) acc[m][n] = (f32x4){0.f, 0.f, 0.f, 0.f};

  for (int kpos = 0; kpos < 9; ++kpos) {
    const int dyr = kpos / 3;
    const int dx = kpos % 3 - 1;
    f16x8 a[2][2];
    #pragma unroll
    for (int mf = 0; mf < 2; ++mf)
      #pragma unroll
      for (int ks = 0; ks < 2; ++ks) {
        int o = (wv << 5) + (mf << 4) + lrow;
        a[mf][ks] = *(const f16x8*)(w0t + o * 576 + (kpos << 6) + (ks << 5) + (lg << 3));
      }
    #pragma unroll
    for (int ks = 0; ks < 2; ++ks)
      #pragma unroll
      for (int nf = 0; nf < 8; ++nf) {
        int xp = (nf << 4) + lrow + dx + 1;
        int cc = ((ks << 5) + (lg << 3)) ^ ((xp & 7) << 3);
        f16x8 bf = *(const f16x8*)(&araw[(dyr * 130 + xp) * 64 + cc]);
        acc[0][nf] = __builtin_amdgcn_mfma_f32_16x16x32_f16(a[0][ks], bf, acc[0][nf], 0, 0, 0);
        acc[1][nf] = __builtin_amdgcn_mfma_f32_16x16x32_f16(a[1][ks], bf, acc[1][nf], 0, 0, 0);
      }
  }

  // epilogue: P[b][y*128+pix][o] f16, + b0
  #pragma unroll
  for (int mf = 0; mf < 2; ++mf) {
    int o0 = (wv << 5) + (mf << 4) + (lg << 2);
    float bb[4];
    #pragma unroll
    for (int r = 0; r < 4; ++r) bb[r] = b0[o0 + r];
    #pragma unroll
    for (int nf = 0; nf < 8; ++nf) {
      int pix = (nf << 4) + lrow;
      u16x4 w;
      #pragma unroll
      for (int r = 0; r < 4; ++r) w[r] = f2h(acc[mf][nf][r] + bb[r]);
      *(u16x4*)(P + ((size_t)((b << 14) + (y << 7) + pix)) * 128 + o0) = w;
    }
  }
}

// ---------------------------------------------------------------------------
// Stage 2: per-block 32 queries x 4 corners = 128 rows through 4 GEMMs.
// actT[r][k^((r&7)<<3)] holds activations^T; weights (A operand) from global.
__global__ __launch_bounds__(256) void k_stage2(
    const U16* __restrict__ P,
    const float* __restrict__ coord, const float* __restrict__ cell,
    const float* __restrict__ w0,
    const U16* __restrict__ w1t, const U16* __restrict__ w2t,
    const U16* __restrict__ w3t, const U16* __restrict__ w4t,
    const float* __restrict__ b1, const float* __restrict__ b2,
    const float* __restrict__ b3, const float* __restrict__ b4,
    float* __restrict__ out)
{
  __shared__ U16 actT[128 * 128];
  const int tid = threadIdx.x, blk = blockIdx.x;

  // ---- h0 prep: row r = corner*32 + qi ----
  {
    int r = tid >> 1, half = tid & 1;
    int corner = r >> 5, qi = r & 31;
    int gq = (blk << 5) + qi;
    float c0v = coord[gq * 2 + 0], c1v = coord[gq * 2 + 1];
    float rc0 = cell[gq * 2 + 0] * 128.0f, rc1 = cell[gq * 2 + 1] * 128.0f;
    int iy, ix; float rel0, rel1;
    corner_calc(c0v, c1v, corner, iy, ix, rel0, rel1);
    int bimg = gq >> 13;
    int lin = iy * 128 + ix;
    const U16* Prow = P + (((size_t)(bimg << 14) + lin) << 7);
    const float* w576 = w0 + 576 * 128;
    const float* w577 = w576 + 128;
    const float* w578 = w577 + 128;
    const float* w579 = w578 + 128;
    for (int j = 0; j < 8; ++j) {
      int n0 = (half << 6) + (j << 3);
      u16x8 pv = *(const u16x8*)(Prow + n0);
      float4 ua = *(const float4*)(w576 + n0), ub = *(const float4*)(w576 + n0 + 4);
      float4 va = *(const float4*)(w577 + n0), vb = *(const float4*)(w577 + n0 + 4);
      float4 sa = *(const float4*)(w578 + n0), sb = *(const float4*)(w578 + n0 + 4);
      float4 ta = *(const float4*)(w579 + n0), tb = *(const float4*)(w579 + n0 + 4);
      float uu[8] = {ua.x,ua.y,ua.z,ua.w,ub.x,ub.y,ub.z,ub.w};
      float vv[8] = {va.x,va.y,va.z,va.w,vb.x,vb.y,vb.z,vb.w};
      float ss[8] = {sa.x,sa.y,sa.z,sa.w,sb.x,sb.y,sb.z,sb.w};
      float tt[8] = {ta.x,ta.y,ta.z,ta.w,tb.x,tb.y,tb.z,tb.w};
      u16x8 res;
      #pragma unroll
      for (int e = 0; e < 8; ++e) {
        float hh = h2f(pv[e]) + rel0 * uu[e] + rel1 * vv[e] + rc0 * ss[e] + rc1 * tt[e];
        res[e] = f2h(fmaxf(hh, 0.0f));
      }
      *(u16x8*)(&actT[(r << 7) + (n0 ^ ((r & 7) << 3))]) = res;
    }
  }
  __syncthreads();

  const int wv = tid >> 6, ln = tid & 63;
  const int lrow = ln & 15, lg = ln >> 4;

  // ---- hidden layers 1..3 ----
  #pragma unroll
  for (int L = 0; L < 3; ++L) {
    const U16* wt = (L == 0) ? w1t : (L == 1) ? w2t : w3t;
    const float* bL = (L == 0) ? b1 : (L == 1) ? b2 : b3;
    f32x4 acc[2][8];
    #pragma unroll
    for (int m = 0; m < 2; ++m)
      #pragma unroll
      for (int n = 0; n < 8; ++n) acc[m][n] = (f32x4){0.f, 0.f, 0.f, 0.f};
    f16x8 a[2][4];
    #pragma unroll
    for (int mf = 0; mf < 2; ++mf)
      #pragma unroll
      for (int ks = 0; ks < 4; ++ks) {
        int o = (wv << 5) + (mf << 4) + lrow;
        a[mf][ks] = *(const f16x8*)(wt + (o << 7) + (ks << 5) + (lg << 3));
      }
    #pragma unroll
    for (int ks = 0; ks < 4; ++ks)
      #pragma unroll
      for (int nf = 0; nf < 8; ++nf) {
        int rr = (nf << 4) + lrow;
        int kk = ((ks << 5) + (lg << 3)) ^ ((rr & 7) << 3);
        f16x8 bf = *(const f16x8*)(&actT[(rr << 7) + kk]);
        acc[0][nf] = __builtin_amdgcn_mfma_f32_16x16x32_f16(a[0][ks], bf, acc[0][nf], 0, 0, 0);
        acc[1][nf] = __builtin_amdgcn_mfma_f32_16x16x32_f16(a[1][ks], bf, acc[1][nf], 0, 0, 0);
      }
    __syncthreads();   // all reads of actT done
    #pragma unroll
    for (int mf = 0; mf < 2; ++mf) {
      int o0 = (wv << 5) + (mf << 4) + (lg << 2);
      float bb[4];
      #pragma unroll
      for (int r = 0; r < 4; ++r) bb[r] = bL[o0 + r];
      #pragma unroll
      for (int nf = 0; nf < 8; ++nf) {
        int rr = (nf << 4) + lrow;
        u16x4 wv4;
        #pragma unroll
        for (int r = 0; r < 4; ++r) wv4[r] = f2h(fmaxf(acc[mf][nf][r] + bb[r], 0.0f));
        *(u16x4*)(&actT[(rr << 7) + (o0 ^ ((rr & 7) << 3))]) = wv4;
      }
    }
    __syncthreads();   // actT ready for next layer
  }

  // ---- final layer 128 -> 64, fused corner combine ----
  f32x4 facc[8];
  #pragma unroll
  for (int n = 0; n < 8; ++n) facc[n] = (f32x4){0.f, 0.f, 0.f, 0.f};
  f16x8 a4[4];
  #pragma unroll
  for (int ks = 0; ks < 4; ++ks) {
    int o = (wv << 4) + lrow;          // 64 outch across 4 waves
    a4[ks] = *(const f16x8*)(w4t + (o << 7) + (ks << 5) + (lg << 3));
  }
  #pragma unroll
  for (int ks = 0; ks < 4; ++ks)
    #pragma unroll
    for (int nf = 0; nf < 8; ++nf) {
      int rr = (nf << 4) + lrow;
      int kk = ((ks << 5) + (lg << 3)) ^ ((rr & 7) << 3);
      f16x8 bf = *(const f16x8*)(&actT[(rr << 7) + kk]);
      facc[nf] = __builtin_amdgcn_mfma_f32_16x16x32_f16(a4[ks], bf, facc[nf], 0, 0, 0);
    }

  // epilogue: lane holds rows {nf*16+lrow}; corners of query qi=nh*16+lrow are nf=2c+nh
  int o0 = (wv << 4) + (lg << 2);
  float b4v[4];
  #pragma unroll
  for (int r = 0; r < 4; ++r) b4v[r] = b4[o0 + r];
  #pragma unroll
  for (int nh = 0; nh < 2; ++nh) {
    int qi = (nh << 4) + lrow;
    int gq = (blk << 5) + qi;
    float c0v = coord[gq * 2 + 0], c1v = coord[gq * 2 + 1];
    float area[4];
    #pragma unroll
    for (int c = 0; c < 4; ++c) {
      int iy, ix; float r0, r1;
      corner_calc(c0v, c1v, c, iy, ix, r0, r1);
      area[c] = fabsf(r0 * r1) + 1e-9f;
    }
    float tot = ((area[0] + area[1]) + area[2]) + area[3];
    float4 res;
    #pragma unroll
    for (int r = 0; r < 4; ++r) {
      float v = facc[nh][r]     * (area[3] / tot);
      v      += facc[2 + nh][r] * (area[2] / tot);
      v      += facc[4 + nh][r] * (area[1] / tot);
      v      += facc[6 + nh][r] * (area[0] / tot);
      res[r] = v + b4v[r];
    }
    float4* dst = (float4*)(out + (size_t)gq * 64 + o0);
    *dst = res;
  }
}

// ---------------------------------------------------------------------------
extern "C" void kernel_launch(void* const* d_in, const int* in_sizes, int n_in,
                              void* d_out, int out_size, void* d_ws, size_t ws_size,
                              hipStream_t stream)
{
  const float* x     = (const float*)d_in[0];
  const float* coord = (const float*)d_in[1];
  const float* cell  = (const float*)d_in[2];
  const float* w0    = (const float*)d_in[3];
  const float* b0    = (const float*)d_in[4];
  const float* w1    = (const float*)d_in[5];
  const float* b1    = (const float*)d_in[6];
  const float* w2    = (const float*)d_in[7];
  const float* b2    = (const float*)d_in[8];
  const float* w3    = (const float*)d_in[9];
  const float* b3    = (const float*)d_in[10];
  const float* w4    = (const float*)d_in[11];
  const float* b4    = (const float*)d_in[12];
  U16* ws = (U16*)d_ws;

  hipLaunchKernelGGL(k_prepw,     dim3(512), dim3(256), 0, stream, w0, w1, w2, w3, w4, ws);
  hipLaunchKernelGGL(k_transpose, dim3(512), dim3(256), 0, stream, x, ws + XT_OFF);
  hipLaunchKernelGGL(k_stage1,    dim3(256), dim3(256), 0, stream,
                     ws + XT_OFF, ws + W0T_OFF, b0, ws + P_OFF);
  hipLaunchKernelGGL(k_stage2,    dim3(512), dim3(256), 0, stream,
                     ws + P_OFF, coord, cell, w0,
                     ws + W1T_OFF, ws + W1T_OFF + 16384, ws + W1T_OFF + 32768, ws + W4T_OFF,
                     b1, b2, b3, b4, (float*)d_out);
}